// Round 3
// baseline (359.010 us; speedup 1.0000x reference)
//
#include <hip/hip_runtime.h>

#define U_NODES 200000
#define B_ROWS  20000
#define K_S     33
#define F_DIM   256
#define E_DIM   128

typedef __bf16 bf16x8 __attribute__((ext_vector_type(8)));
typedef float  f32x4  __attribute__((ext_vector_type(4)));
typedef unsigned short ushortx8 __attribute__((ext_vector_type(8)));

__device__ __forceinline__ unsigned short f2bf(float f) {
    unsigned int u = __builtin_bit_cast(unsigned int, f);
    u += 0x7fffu + ((u >> 16) & 1u);            // round-to-nearest-even
    return (unsigned short)(u >> 16);
}

// ---------------------------------------------------------------------------
// One-time prep: Wt[n][k] = bf16(W[k][n]) so B-fragments are contiguous-k.
// ---------------------------------------------------------------------------
__global__ void wprep_kernel(const float* __restrict__ W, unsigned short* __restrict__ Wt) {
    int n = blockIdx.x;      // 128
    int k = threadIdx.x;     // 256
    Wt[n * F_DIM + k] = f2bf(W[(size_t)k * E_DIM + n]);
}

// ---------------------------------------------------------------------------
// Barrier-free-K-loop MFMA GEMM: h = bf16(A @ W), fused BN column stats.
//  - Entire Wt (64 KB bf16) staged into LDS ONCE, XOR-swizzled on 16B octets
//    (bank group = (octet^row)&7 -> <=2-way aliasing on ds_read_b128 = free).
//  - A has no cross-wave reuse -> loaded fragment-direct from global
//    (16 rows x 128B contiguous segments per dwordx4 pair), cvt->bf16 in regs.
//  - NO __syncthreads in the K-loop: compiler hoists kf+1 loads over kf MFMAs.
// Block: 128 rows x 128 cols; wave wv owns rows [wv*32, wv*32+32).
// ---------------------------------------------------------------------------
__global__ __launch_bounds__(256) void gemm_stats_kernel(
    const float* __restrict__ A, const unsigned short* __restrict__ Wt,
    unsigned short* __restrict__ h, float* __restrict__ gsum, float* __restrict__ gsq)
{
    __shared__ __attribute__((aligned(16))) char smem[65536];   // Ws[128 n][256 k] bf16, swizzled

    const int t    = threadIdx.x;
    const int lane = t & 63;
    const int wv   = t >> 6;
    const int m    = lane & 15;
    const int qd   = lane >> 4;
    const int row0 = blockIdx.x * 128;

    // ---- stage ALL of Wt once ----
    #pragma unroll
    for (int i = 0; i < 16; ++i) {
        int of = t + 256 * i;          // 16B-octet index, 0..4095
        int n = of >> 5, o = of & 31;
        ushortx8 v = *(const ushortx8*)(Wt + n * F_DIM + o * 8);
        *(ushortx8*)(smem + n * 512 + ((o ^ (n & 7)) << 4)) = v;
    }
    __syncthreads();

    const int r0 = row0 + wv * 32 + m;
    const int r1 = r0 + 16;
    const float* A0 = A + (size_t)min(r0, U_NODES - 1) * F_DIM + qd * 8;
    const float* A1 = A + (size_t)min(r1, U_NODES - 1) * F_DIM + qd * 8;

    f32x4 acc0[8], acc1[8];
    #pragma unroll
    for (int ct = 0; ct < 8; ++ct) {
        acc0[ct] = (f32x4){0.f, 0.f, 0.f, 0.f};
        acc1[ct] = (f32x4){0.f, 0.f, 0.f, 0.f};
    }

    #pragma unroll
    for (int kf = 0; kf < 8; ++kf) {
        float a0f[8], a1f[8];
        *(float4*)&a0f[0] = *(const float4*)(A0 + kf * 32);
        *(float4*)&a0f[4] = *(const float4*)(A0 + kf * 32 + 4);
        *(float4*)&a1f[0] = *(const float4*)(A1 + kf * 32);
        *(float4*)&a1f[4] = *(const float4*)(A1 + kf * 32 + 4);
        ushortx8 u0, u1;
        #pragma unroll
        for (int j = 0; j < 8; ++j) { u0[j] = f2bf(a0f[j]); u1[j] = f2bf(a1f[j]); }
        bf16x8 a0 = __builtin_bit_cast(bf16x8, u0);
        bf16x8 a1 = __builtin_bit_cast(bf16x8, u1);
        #pragma unroll
        for (int ct = 0; ct < 8; ++ct) {
            int n = ct * 16 + m;
            bf16x8 b = *(const bf16x8*)(smem + n * 512 + (((kf * 4 + qd) ^ (n & 7)) << 4));
            acc0[ct] = __builtin_amdgcn_mfma_f32_16x16x32_bf16(a0, b, acc0[ct], 0, 0, 0);
            acc1[ct] = __builtin_amdgcn_mfma_f32_16x16x32_bf16(a1, b, acc1[ct], 0, 0, 0);
        }
    }
    __syncthreads();   // Ws reads done; smem can be reused

    // ---- fused BN stats (D layout m89: col=lane&15, row=(lane>>4)*4+reg) ----
    const bool full = (row0 + 128) <= U_NODES;
    float s[8], sq[8];
    #pragma unroll
    for (int ct = 0; ct < 8; ++ct) {
        float ss = 0.f, qq = 0.f;
        #pragma unroll
        for (int v = 0; v < 4; ++v) {
            float x0 = acc0[ct][v];
            float x1 = acc1[ct][v];
            if (full || (row0 + wv * 32 + qd * 4 + v) < U_NODES)      { ss += x0; qq += x0 * x0; }
            if (full || (row0 + wv * 32 + 16 + qd * 4 + v) < U_NODES) { ss += x1; qq += x1 * x1; }
        }
        s[ct] = ss; sq[ct] = qq;
    }
    float* red = (float*)smem;   // [16][128]
    int rq = wv * 4 + qd;
    #pragma unroll
    for (int ct = 0; ct < 8; ++ct) red[rq * 128 + ct * 16 + m] = s[ct];
    __syncthreads();
    if (t < 128) {
        float tot = 0.f;
        #pragma unroll
        for (int i = 0; i < 16; ++i) tot += red[i * 128 + t];
        atomicAdd(&gsum[t], tot);
    }
    __syncthreads();
    #pragma unroll
    for (int ct = 0; ct < 8; ++ct) red[rq * 128 + ct * 16 + m] = sq[ct];
    __syncthreads();
    if (t < 128) {
        float tot = 0.f;
        #pragma unroll
        for (int i = 0; i < 16; ++i) tot += red[i * 128 + t];
        atomicAdd(&gsq[t], tot);
    }
    __syncthreads();

    // ---- h store: acc layout -> per-wave LDS transpose -> coalesced bf16x8 stores ----
    unsigned short* tb = (unsigned short*)(smem + wv * 8192);   // [32][128] per wave
    #pragma unroll
    for (int ct = 0; ct < 8; ++ct)
        #pragma unroll
        for (int v = 0; v < 4; ++v) {
            tb[(qd * 4 + v) * 128 + ct * 16 + m]      = f2bf(acc0[ct][v]);
            tb[(16 + qd * 4 + v) * 128 + ct * 16 + m] = f2bf(acc1[ct][v]);
        }
    #pragma unroll
    for (int i = 0; i < 8; ++i) {
        int idx = lane + 64 * i;            // 0..511
        int r = idx >> 4, c8 = (idx & 15) * 8;
        int gr = row0 + wv * 32 + r;
        if (gr < U_NODES)
            *(ushortx8*)(h + (size_t)gr * E_DIM + c8) = *(const ushortx8*)(tb + r * 128 + c8);
    }
}

// ---------------------------------------------------------------------------
// Fold BN stats + gamma/beta into per-column scale/shift.
// ---------------------------------------------------------------------------
__global__ void finalize_kernel(const float* __restrict__ gsum, const float* __restrict__ gsq,
                                const float* __restrict__ gamma, const float* __restrict__ beta,
                                float* __restrict__ scale, float* __restrict__ shift)
{
    int e = threadIdx.x;
    float mu  = gsum[e] * (1.f / U_NODES);
    float var = gsq[e] * (1.f / U_NODES) - mu * mu;
    float inv = rsqrtf(var + 1e-5f);
    float sc  = gamma[e] * inv;
    scale[e] = sc;
    shift[e] = beta[e] - sc * mu;
}

// ---------------------------------------------------------------------------
// Gather + BN + tanh + mean. ONE WAVE PER OUTPUT ROW: lane covers cols
// {2l, 2l+1} via one uint (2 bf16) load -> 33 independent 1-VGPR loads in
// flight, scalar-base addressing via readfirstlane (idx is wave-uniform).
// ---------------------------------------------------------------------------
__global__ __launch_bounds__(256) void gather_kernel(
    const unsigned short* __restrict__ h, const int* __restrict__ sidx_g,
    const float* __restrict__ scale, const float* __restrict__ shift,
    float* __restrict__ out)
{
    __shared__ int sl[4 * K_S];
    const int t    = threadIdx.x;
    const int lane = t & 63;
    const int wv   = t >> 6;
    const int b0   = blockIdx.x * 4;
    for (int i = t; i < 4 * K_S; i += 256) sl[i] = sidx_g[(size_t)b0 * K_S + i];
    float2 sc = *(const float2*)(scale + lane * 2);
    float2 sh = *(const float2*)(shift + lane * 2);
    __syncthreads();

    float acc0 = 0.f, acc1 = 0.f;
    #pragma unroll
    for (int k = 0; k < K_S; ++k) {
        int idx = __builtin_amdgcn_readfirstlane(sl[wv * K_S + k]);
        unsigned int v = *(const unsigned int*)(h + (size_t)idx * E_DIM + lane * 2);
        float x0 = __builtin_bit_cast(float, v << 16)         * sc.x + sh.x;  // col 2l
        float x1 = __builtin_bit_cast(float, v & 0xffff0000u) * sc.y + sh.y;  // col 2l+1
        acc0 += 1.f - 2.f * __builtin_amdgcn_rcpf(__expf(2.f * x0) + 1.f);    // tanh
        acc1 += 1.f - 2.f * __builtin_amdgcn_rcpf(__expf(2.f * x1) + 1.f);
    }
    *(float2*)(out + (size_t)(b0 + wv) * E_DIM + lane * 2) =
        make_float2(acc0 * (1.f / K_S), acc1 * (1.f / K_S));
}

// ---------------------------------------------------------------------------
extern "C" void kernel_launch(void* const* d_in, const int* in_sizes, int n_in,
                              void* d_out, int out_size, void* d_ws, size_t ws_size,
                              hipStream_t stream) {
    const float* features = (const float*)d_in[0];
    const float* W        = (const float*)d_in[1];
    // d_in[2] = bias — provably cancels inside BatchNorm; unused.
    const float* gamma    = (const float*)d_in[3];
    const float* beta     = (const float*)d_in[4];
    const int*   sample   = (const int*)d_in[5];
    float* out = (float*)d_out;

    // ws layout: gsum[128] gsq[128] scale[128] shift[128] | Wt[128*256 bf16] | h[U*128 bf16]
    float* gsum  = (float*)d_ws;
    float* gsq   = gsum + 128;
    float* scale = gsq + 128;
    float* shift = scale + 128;
    unsigned short* Wt = (unsigned short*)(shift + 128);
    unsigned short* h  = Wt + 128 * 256;

    hipMemsetAsync(gsum, 0, 2 * 128 * sizeof(float), stream);
    wprep_kernel<<<128, 256, 0, stream>>>(W, Wt);
    gemm_stats_kernel<<<(U_NODES + 127) / 128, 256, 0, stream>>>(features, Wt, h, gsum, gsq);
    finalize_kernel<<<1, 128, 0, stream>>>(gsum, gsq, gamma, beta, scale, shift);
    gather_kernel<<<B_ROWS / 4, 256, 0, stream>>>(h, sample, scale, shift, out);
}